// Round 12
// baseline (382.364 us; speedup 1.0000x reference)
//
#include <hip/hip_runtime.h>
#include <hip/hip_bf16.h>
#include <math.h>

typedef unsigned short u16;
typedef unsigned int   u32;
typedef short  short8 __attribute__((ext_vector_type(8)));
typedef float  f32x4  __attribute__((ext_vector_type(4)));

#define EMB 512
#define BB  8192
#define KDIM 2048   // 4*EMB
#define SLICEF 4194304   // BB*EMB floats per l-slice (16 MB)
#define HALFF  2097152   // half slice in floats

__device__ inline u16 f2b(float f) {
    union { float f; u32 u; } v; v.f = f;
    u32 r = v.u + 0x7fffu + ((v.u >> 16) & 1u);   // round-to-nearest-even
    return (u16)(r >> 16);
}

// non-temporal float4 load via native ext_vector (HIP float4 struct is rejected)
__device__ inline f32x4 ntload(const float* p) {
    return __builtin_nontemporal_load((const f32x4*)p);
}

__device__ inline void store_bf4(u16* dst, f32x4 a, float s) {
    *(uint2*)dst = make_uint2((u32)f2b(a.x*s) | ((u32)f2b(a.y*s) << 16),
                              (u32)f2b(a.z*s) | ((u32)f2b(a.w*s) << 16));
}

// ---------------- Kernel 1: W1 f32 -> bf16 ----------------
__global__ __launch_bounds__(256) void k_w1(const float4* __restrict__ w, u16* __restrict__ o) {
    int i = blockIdx.x * 256 + threadIdx.x;   // 262144 threads * 4 floats = 1048576
    float4 v = w[i];
    u32 lo = (u32)f2b(v.x) | ((u32)f2b(v.y) << 16);
    u32 hi = (u32)f2b(v.z) | ((u32)f2b(v.w) << 16);
    *(uint2*)(o + (size_t)i * 4) = make_uint2(lo, hi);
}

// ---------------- Kernel 2a: full means, GPU-wide coherent sweep ----------------
// Probe-pattern (R10: 5.6 TB/s): 2048 blocks x 256 threads = 524288 threads.
// Thread t owns within-slice float4 positions p0 = t and p1 = t + 512K, i.e.
// (b, d:4) with b = t>>7, d = (t&127)*4, and (b+4096, d:4). Looping l = 0..31,
// the whole GPU reads each 16 MB l-slice as one contiguous window in address
// order -- the exact access sequence the probe sustained at 5.6 TB/s.
// Per-(b,d) accumulation order over l is sequential -> bitwise identical.
__global__ __launch_bounds__(256) void k_meanfull(const float* __restrict__ vqu,
                                                  const float* __restrict__ van,
                                                  u16* __restrict__ pooled)
{
    const size_t t  = (size_t)blockIdx.x * 256 + threadIdx.x;   // 0..524287
    const int   b0  = (int)(t >> 7);
    const int   d0  = ((int)t & 127) * 4;
    const float iv  = 1.0f / 32.0f;

    // ---- vqu -> section 1 ----
    {
        const float* p = vqu + t * 4;
        f32x4 a0 = {0.f,0.f,0.f,0.f}, a1 = a0;
        #pragma unroll 4
        for (int l = 0; l < 32; ++l) {
            const float* r = p + (size_t)l * SLICEF;
            f32x4 v0 = ntload(r);
            f32x4 v1 = ntload(r + HALFF);
            a0 += v0; a1 += v1;
        }
        store_bf4(pooled + (size_t)b0 * KDIM + EMB + d0,            a0, iv);
        store_bf4(pooled + (size_t)(b0 + 4096) * KDIM + EMB + d0,   a1, iv);
    }
    // ---- van -> section 3 ----
    {
        const float* p = van + t * 4;
        f32x4 a0 = {0.f,0.f,0.f,0.f}, a1 = a0;
        #pragma unroll 4
        for (int l = 0; l < 32; ++l) {
            const float* r = p + (size_t)l * SLICEF;
            f32x4 v0 = ntload(r);
            f32x4 v1 = ntload(r + HALFF);
            a0 += v0; a1 += v1;
        }
        store_bf4(pooled + (size_t)b0 * KDIM + 3 * EMB + d0,          a0, iv);
        store_bf4(pooled + (size_t)(b0 + 4096) * KDIM + 3 * EMB + d0, a1, iv);
    }
}

// ---------------- Kernel 2b: masked means, same sweep pattern ----------------
// A wave's 64 lanes share one b (128 threads per b, 64-aligned) -> lengths are
// wave-uniform scalar branches; exact per-b traffic; l order sequential.
__global__ __launch_bounds__(256) void k_meanmask(
    const float* __restrict__ qv, const int* __restrict__ qlen,
    const float* __restrict__ av, const int* __restrict__ alen,
    u16* __restrict__ pooled)
{
    const size_t t  = (size_t)blockIdx.x * 256 + threadIdx.x;   // 0..524287
    const int   b0  = (int)(t >> 7);
    const int   d0  = ((int)t & 127) * 4;

    // ---- qv -> section 0 (LQ=32) ----
    {
        const int nA = __builtin_amdgcn_readfirstlane(qlen[b0]);
        const int nB = __builtin_amdgcn_readfirstlane(qlen[b0 + 4096]);
        const int mx = nA > nB ? nA : nB;
        const float* p = qv + t * 4;
        f32x4 a0 = {0.f,0.f,0.f,0.f}, a1 = a0;
        #pragma unroll 2
        for (int l = 0; l < mx; ++l) {
            const float* r = p + (size_t)l * SLICEF;
            if (l < nA) a0 += ntload(r);
            if (l < nB) a1 += ntload(r + HALFF);
        }
        store_bf4(pooled + (size_t)b0 * KDIM + d0,          a0, 1.0f / (float)nA);
        store_bf4(pooled + (size_t)(b0 + 4096) * KDIM + d0, a1, 1.0f / (float)nB);
    }
    // ---- av -> section 2 (LA=16) ----
    {
        const int nA = __builtin_amdgcn_readfirstlane(alen[b0]);
        const int nB = __builtin_amdgcn_readfirstlane(alen[b0 + 4096]);
        const int mx = nA > nB ? nA : nB;
        const float* p = av + t * 4;
        f32x4 a0 = {0.f,0.f,0.f,0.f}, a1 = a0;
        #pragma unroll 2
        for (int l = 0; l < mx; ++l) {
            const float* r = p + (size_t)l * SLICEF;
            if (l < nA) a0 += ntload(r);
            if (l < nB) a1 += ntload(r + HALFF);
        }
        store_bf4(pooled + (size_t)b0 * KDIM + 2 * EMB + d0,          a0, 1.0f / (float)nA);
        store_bf4(pooled + (size_t)(b0 + 4096) * KDIM + 2 * EMB + d0, a1, 1.0f / (float)nB);
    }
}

// ---------------- Kernel 3: GEMM h = pooled @ W1^T, + bias + exact GELU ----------------
#define GBM 128
#define GBN 128
#define GBK 64
__global__ __launch_bounds__(256) void k_gemm(
    const u16* __restrict__ A, const u16* __restrict__ Bw,
    const float* __restrict__ bias, float* __restrict__ H)
{
    __shared__ u16 As[GBM * GBK];   // 16 KB, logical [128][64], groups of 8 swizzled
    __shared__ u16 Bs[GBN * GBK];   // 16 KB

    const int tid  = threadIdx.x;
    const int lane = tid & 63;
    const int wid  = tid >> 6;                 // 0..3
    const int wr   = wid >> 1;                 // 0..1 (row quadrant)
    const int wc   = wid & 1;                  // 0..1 (col quadrant)
    const int brow = blockIdx.y * GBM;
    const int bcol = blockIdx.x * GBN;

    const int lrow = lane & 15;
    const int lko  = (lane >> 4) * 8;          // k sub-offset within 32
    const int gsub = lko >> 3;                 // 0..3 (group within kk half)

    f32x4 acc[4][4];
    #pragma unroll
    for (int m = 0; m < 4; ++m)
        #pragma unroll
        for (int n = 0; n < 4; ++n)
            acc[m][n] = (f32x4){0.f, 0.f, 0.f, 0.f};

    for (int kt = 0; kt < KDIM / GBK; ++kt) {
        const int k0 = kt * GBK;
        #pragma unroll
        for (int i = 0; i < 4; ++i) {
            int f   = i * 256 + tid;           // 0..1023
            int row = f >> 3;
            int gl  = (f & 7) ^ (row & 7);     // source (logical) group
            const u16* srcA = A  + (size_t)(brow + row) * KDIM + k0 + gl * 8;
            const u16* srcB = Bw + (size_t)(bcol + row) * KDIM + k0 + gl * 8;
            __builtin_amdgcn_global_load_lds(
                (const __attribute__((address_space(1))) void*)srcA,
                (__attribute__((address_space(3))) void*)&As[f * 8], 16, 0, 0);
            __builtin_amdgcn_global_load_lds(
                (const __attribute__((address_space(1))) void*)srcB,
                (__attribute__((address_space(3))) void*)&Bs[f * 8], 16, 0, 0);
        }
        __syncthreads();
        #pragma unroll
        for (int kk = 0; kk < 2; ++kk) {
            const int glog = kk * 4 + gsub;    // logical group 0..7
            short8 bfrag[4];
            #pragma unroll
            for (int n = 0; n < 4; ++n) {
                int row = wc * 64 + n * 16 + lrow;
                bfrag[n] = *(const short8*)&Bs[row * GBK + ((glog ^ (row & 7)) * 8)];
            }
            #pragma unroll
            for (int m = 0; m < 4; ++m) {
                int row = wr * 64 + m * 16 + lrow;
                short8 afrag = *(const short8*)&As[row * GBK + ((glog ^ (row & 7)) * 8)];
                #pragma unroll
                for (int n = 0; n < 4; ++n)
                    acc[m][n] = __builtin_amdgcn_mfma_f32_16x16x32_bf16(
                        afrag, bfrag[n], acc[m][n], 0, 0, 0);
            }
        }
        __syncthreads();
    }

    #pragma unroll
    for (int m = 0; m < 4; ++m) {
        const int row0 = brow + wr * 64 + m * 16 + (lane >> 4) * 4;
        #pragma unroll
        for (int n = 0; n < 4; ++n) {
            const int col = bcol + wc * 64 + n * 16 + (lane & 15);
            const float bv = bias[col];
            #pragma unroll
            for (int r = 0; r < 4; ++r) {
                float x = acc[m][n][r] + bv;
                float g = 0.5f * x * (1.0f + erff(x * 0.70710678118654752f));
                H[(size_t)(row0 + r) * EMB + col] = g;
            }
        }
    }
}

// ---------------- Kernel 4: BN partial stats (deterministic, no atomics) ----------------
__global__ __launch_bounds__(512) void k_stats(const float* __restrict__ H,
                                               float* __restrict__ psum,
                                               float* __restrict__ psq)
{
    const int f = threadIdx.x;   // 0..511
    const int j = blockIdx.x;    // 0..255
    const float* p = H + (size_t)j * 32 * EMB + f;
    float s = 0.f, ss = 0.f;
    #pragma unroll 4
    for (int r = 0; r < 32; ++r) {
        float v = p[(size_t)r * EMB];
        s += v; ss += v * v;
    }
    psum[j * EMB + f] = s;
    psq [j * EMB + f] = ss;
}

// ---------------- Kernel 5: fold BN + W2 into coeff[512] and const ----------------
__global__ __launch_bounds__(512) void k_fin(const float* __restrict__ psum,
                                             const float* __restrict__ psq,
                                             const float* __restrict__ gamma,
                                             const float* __restrict__ beta,
                                             const float* __restrict__ W2,
                                             const float* __restrict__ b2,
                                             float* __restrict__ coeff)
{
    const int f = threadIdx.x;
    float s = 0.f, ss = 0.f;
    for (int j = 0; j < 256; ++j) { s += psum[j * EMB + f]; ss += psq[j * EMB + f]; }
    const float invB = 1.0f / 8192.0f;
    float mu  = s * invB;
    float var = ss * invB - mu * mu;
    float rs  = rsqrtf(var + 1e-5f);
    float c   = gamma[f] * rs * W2[f];
    coeff[f]  = c;
    float kterm = beta[f] * W2[f] - mu * c;

    __shared__ float red[512];
    red[f] = kterm;
    __syncthreads();
    for (int s2 = 256; s2 > 0; s2 >>= 1) {
        if (f < s2) red[f] += red[f + s2];
        __syncthreads();
    }
    if (f == 0) coeff[512] = red[0] + b2[0];
}

// ---------------- Kernel 6: logits[b] = dot(h[b,:], coeff) + const ----------------
__global__ __launch_bounds__(64) void k_logits(const float* __restrict__ H,
                                               const float* __restrict__ coeff,
                                               float* __restrict__ out)
{
    const int b = blockIdx.x;
    const int l = threadIdx.x;   // 0..63
    const float4* hp = (const float4*)(H + (size_t)b * EMB);
    const float4* cp = (const float4*)coeff;
    float4 h0 = hp[l],      c0 = cp[l];
    float4 h1 = hp[l + 64], c1 = cp[l + 64];
    float p = h0.x * c0.x + h0.y * c0.y + h0.z * c0.z + h0.w * c0.w
            + h1.x * c1.x + h1.y * c1.y + h1.z * c1.z + h1.w * c1.w;
    #pragma unroll
    for (int off = 32; off > 0; off >>= 1) p += __shfl_down(p, off);
    if (l == 0) out[b] = p + coeff[512];
}

extern "C" void kernel_launch(void* const* d_in, const int* in_sizes, int n_in,
                              void* d_out, int out_size, void* d_ws, size_t ws_size,
                              hipStream_t stream) {
    (void)in_sizes; (void)n_in; (void)out_size; (void)ws_size;
    const float* qv    = (const float*)d_in[0];
    const float* vqu   = (const float*)d_in[1];
    const int*   qlen  = (const int*)d_in[2];
    const float* av    = (const float*)d_in[3];
    const float* van   = (const float*)d_in[4];
    const int*   alen  = (const int*)d_in[5];
    const float* W1    = (const float*)d_in[6];
    const float* b1    = (const float*)d_in[7];
    const float* gamma = (const float*)d_in[8];
    const float* beta  = (const float*)d_in[9];
    const float* W2    = (const float*)d_in[10];
    const float* b2    = (const float*)d_in[11];
    float* out = (float*)d_out;

    char* ws = (char*)d_ws;
    u16*   pooled = (u16*)(ws);                      // 8192*2048*2      = 33,554,432
    u16*   w1b    = (u16*)(ws + 33554432);           // 512*2048*2       =  2,097,152
    float* H      = (float*)(ws + 35651584);         // 8192*512*4       = 16,777,216
    float* psum   = (float*)(ws + 52428800);         // 256*512*4        =    524,288
    float* psq    = (float*)(ws + 52953088);         // 256*512*4        =    524,288
    float* coeff  = (float*)(ws + 53477376);         // 513*4

    k_w1      <<<dim3(1024),   dim3(256), 0, stream>>>((const float4*)W1, w1b);
    k_meanfull<<<dim3(2048),   dim3(256), 0, stream>>>(vqu, van, pooled);
    k_meanmask<<<dim3(2048),   dim3(256), 0, stream>>>(qv, qlen, av, alen, pooled);
    k_gemm    <<<dim3(4, 64),  dim3(256), 0, stream>>>(pooled, w1b, b1, H);
    k_stats   <<<dim3(256),    dim3(512), 0, stream>>>(H, psum, psq);
    k_fin     <<<dim3(1),      dim3(512), 0, stream>>>(psum, psq, gamma, beta, W2, b2, coeff);
    k_logits  <<<dim3(8192),   dim3(64),  0, stream>>>(H, coeff, out);
}

// Round 13
// 344.579 us; speedup vs baseline: 1.1097x; 1.1097x over previous
//
#include <hip/hip_runtime.h>
#include <hip/hip_bf16.h>
#include <math.h>

typedef unsigned short u16;
typedef unsigned int   u32;
typedef short  short8 __attribute__((ext_vector_type(8)));
typedef float  f32x4  __attribute__((ext_vector_type(4)));

#define EMB 512
#define BB  8192
#define KDIM 2048   // 4*EMB

__device__ inline u16 f2b(float f) {
    union { float f; u32 u; } v; v.f = f;
    u32 r = v.u + 0x7fffu + ((v.u >> 16) & 1u);   // round-to-nearest-even
    return (u16)(r >> 16);
}

// non-temporal float4 load via native ext_vector (HIP float4 struct is rejected)
__device__ inline f32x4 ntload(const float* p) {
    return __builtin_nontemporal_load((const f32x4*)p);
}

// ---------------- Kernel 1: W1 f32 -> bf16 ----------------
__global__ __launch_bounds__(256) void k_w1(const float4* __restrict__ w, u16* __restrict__ o) {
    int i = blockIdx.x * 256 + threadIdx.x;   // 262144 threads * 4 floats = 1048576
    float4 v = w[i];
    u32 lo = (u32)f2b(v.x) | ((u32)f2b(v.y) << 16);
    u32 hi = (u32)f2b(v.z) | ((u32)f2b(v.w) << 16);
    *(uint2*)(o + (size_t)i * 4) = make_uint2(lo, hi);
}

// ---------------- Kernel 2: ALL pooling in one kernel (R6-proven bodies) ----------------
// 512 blocks x 256 threads. Part 1 = R6 meanfull (blocks [0,256) vqu, [256,512)
// van; wave owns 8 b's, 16 KB contiguous per l-step). Part 2 = R6 meanmask
// (wave owns 4 b's, wave-uniform scalar len guards, exact traffic). Merging
// removes a launch boundary and makes pool time directly visible in top-5.
// Per-(b,d) accumulation order over l is sequential -> bitwise-identical.
__global__ __launch_bounds__(256) void k_pool(
    const float* __restrict__ qv, const float* __restrict__ vqu, const int* __restrict__ qlen,
    const float* __restrict__ av, const float* __restrict__ van, const int* __restrict__ alen,
    u16* __restrict__ pooled)
{
    const int tid  = threadIdx.x;
    const int ln   = tid & 63;
    const size_t rowf = (size_t)BB * EMB;      // floats per l-slice

    // ================= Part 1: full means (vqu -> sec1, van -> sec3) =================
    {
        int bid = blockIdx.x;
        const float* src; int sec;
        if (bid < 256) { src = vqu; sec = 1; }
        else           { src = van; sec = 3; bid -= 256; }
        const int g = bid * 4 + (tid >> 6);    // 0..1023

        f32x4 acc[16];
        #pragma unroll
        for (int j = 0; j < 16; ++j) acc[j] = (f32x4){0.f, 0.f, 0.f, 0.f};

        const float* p0 = src + (size_t)g * 4096 + ln * 4;
        for (int l = 0; l < 32; ++l) {
            const float* p = p0 + (size_t)l * rowf;
            f32x4 v[16];
            #pragma unroll
            for (int j = 0; j < 16; ++j) v[j] = ntload(p + j * 256);
            #pragma unroll
            for (int j = 0; j < 16; ++j) acc[j] += v[j];
        }

        const int bA = g * 8;
        const float iv = 1.0f / 32.0f;
        #pragma unroll
        for (int j = 0; j < 16; ++j) {
            f32x4 a = acc[j];
            u16* dst = pooled + (size_t)(bA + (j >> 1)) * KDIM + sec * EMB
                     + (j & 1) * 256 + ln * 4;
            *(uint2*)dst = make_uint2((u32)f2b(a.x*iv) | ((u32)f2b(a.y*iv) << 16),
                                      (u32)f2b(a.z*iv) | ((u32)f2b(a.w*iv) << 16));
        }
    }

    // ================= Part 2: masked means (qv -> sec0, av -> sec2) =================
    {
        const int w    = tid >> 6;
        const int lane = tid & 63;
        const int bA   = blockIdx.x * 16 + w * 4;   // wave handles bA..bA+3

        // ---------- q section (LQ=32) ----------
        {
            const int n0 = __builtin_amdgcn_readfirstlane(qlen[bA]);
            const int n1 = __builtin_amdgcn_readfirstlane(qlen[bA + 1]);
            const int n2 = __builtin_amdgcn_readfirstlane(qlen[bA + 2]);
            const int n3 = __builtin_amdgcn_readfirstlane(qlen[bA + 3]);
            int mx = n0 > n1 ? n0 : n1;
            mx = mx > n2 ? mx : n2; mx = mx > n3 ? mx : n3;
            f32x4 a0 = {0,0,0,0}, b0 = a0, a1 = a0, b1 = a0,
                  a2 = a0, b2 = a0, a3 = a0, b3 = a0;
            const float* p = qv + (size_t)bA * EMB + lane * 4;
            for (int l = 0; l < mx; ++l) {
                const float* r = p + (size_t)l * rowf;
                if (l < n0) { f32x4 v = ntload(r),        u = ntload(r + 256);  a0 += v; b0 += u; }
                if (l < n1) { f32x4 v = ntload(r + 512),  u = ntload(r + 768);  a1 += v; b1 += u; }
                if (l < n2) { f32x4 v = ntload(r + 1024), u = ntload(r + 1280); a2 += v; b2 += u; }
                if (l < n3) { f32x4 v = ntload(r + 1536), u = ntload(r + 1792); a3 += v; b3 += u; }
            }
            const float i0 = 1.0f/(float)n0, i1 = 1.0f/(float)n1,
                        i2 = 1.0f/(float)n2, i3 = 1.0f/(float)n3;
            u16* d0 = pooled + (size_t)(bA    ) * KDIM + lane * 4;
            u16* d1 = pooled + (size_t)(bA + 1) * KDIM + lane * 4;
            u16* d2 = pooled + (size_t)(bA + 2) * KDIM + lane * 4;
            u16* d3 = pooled + (size_t)(bA + 3) * KDIM + lane * 4;
            *(uint2*)(d0      ) = make_uint2((u32)f2b(a0.x*i0) | ((u32)f2b(a0.y*i0) << 16),
                                             (u32)f2b(a0.z*i0) | ((u32)f2b(a0.w*i0) << 16));
            *(uint2*)(d0 + 256) = make_uint2((u32)f2b(b0.x*i0) | ((u32)f2b(b0.y*i0) << 16),
                                             (u32)f2b(b0.z*i0) | ((u32)f2b(b0.w*i0) << 16));
            *(uint2*)(d1      ) = make_uint2((u32)f2b(a1.x*i1) | ((u32)f2b(a1.y*i1) << 16),
                                             (u32)f2b(a1.z*i1) | ((u32)f2b(a1.w*i1) << 16));
            *(uint2*)(d1 + 256) = make_uint2((u32)f2b(b1.x*i1) | ((u32)f2b(b1.y*i1) << 16),
                                             (u32)f2b(b1.z*i1) | ((u32)f2b(b1.w*i1) << 16));
            *(uint2*)(d2      ) = make_uint2((u32)f2b(a2.x*i2) | ((u32)f2b(a2.y*i2) << 16),
                                             (u32)f2b(a2.z*i2) | ((u32)f2b(a2.w*i2) << 16));
            *(uint2*)(d2 + 256) = make_uint2((u32)f2b(b2.x*i2) | ((u32)f2b(b2.y*i2) << 16),
                                             (u32)f2b(b2.z*i2) | ((u32)f2b(b2.w*i2) << 16));
            *(uint2*)(d3      ) = make_uint2((u32)f2b(a3.x*i3) | ((u32)f2b(a3.y*i3) << 16),
                                             (u32)f2b(a3.z*i3) | ((u32)f2b(a3.w*i3) << 16));
            *(uint2*)(d3 + 256) = make_uint2((u32)f2b(b3.x*i3) | ((u32)f2b(b3.y*i3) << 16),
                                             (u32)f2b(b3.z*i3) | ((u32)f2b(b3.w*i3) << 16));
        }
        // ---------- a section (LA=16) ----------
        {
            const int n0 = __builtin_amdgcn_readfirstlane(alen[bA]);
            const int n1 = __builtin_amdgcn_readfirstlane(alen[bA + 1]);
            const int n2 = __builtin_amdgcn_readfirstlane(alen[bA + 2]);
            const int n3 = __builtin_amdgcn_readfirstlane(alen[bA + 3]);
            int mx = n0 > n1 ? n0 : n1;
            mx = mx > n2 ? mx : n2; mx = mx > n3 ? mx : n3;
            f32x4 a0 = {0,0,0,0}, b0 = a0, a1 = a0, b1 = a0,
                  a2 = a0, b2 = a0, a3 = a0, b3 = a0;
            const float* p = av + (size_t)bA * EMB + lane * 4;
            for (int l = 0; l < mx; ++l) {
                const float* r = p + (size_t)l * rowf;
                if (l < n0) { f32x4 v = ntload(r),        u = ntload(r + 256);  a0 += v; b0 += u; }
                if (l < n1) { f32x4 v = ntload(r + 512),  u = ntload(r + 768);  a1 += v; b1 += u; }
                if (l < n2) { f32x4 v = ntload(r + 1024), u = ntload(r + 1280); a2 += v; b2 += u; }
                if (l < n3) { f32x4 v = ntload(r + 1536), u = ntload(r + 1792); a3 += v; b3 += u; }
            }
            const float i0 = 1.0f/(float)n0, i1 = 1.0f/(float)n1,
                        i2 = 1.0f/(float)n2, i3 = 1.0f/(float)n3;
            u16* d0 = pooled + (size_t)(bA    ) * KDIM + 2 * EMB + lane * 4;
            u16* d1 = pooled + (size_t)(bA + 1) * KDIM + 2 * EMB + lane * 4;
            u16* d2 = pooled + (size_t)(bA + 2) * KDIM + 2 * EMB + lane * 4;
            u16* d3 = pooled + (size_t)(bA + 3) * KDIM + 2 * EMB + lane * 4;
            *(uint2*)(d0      ) = make_uint2((u32)f2b(a0.x*i0) | ((u32)f2b(a0.y*i0) << 16),
                                             (u32)f2b(a0.z*i0) | ((u32)f2b(a0.w*i0) << 16));
            *(uint2*)(d0 + 256) = make_uint2((u32)f2b(b0.x*i0) | ((u32)f2b(b0.y*i0) << 16),
                                             (u32)f2b(b0.z*i0) | ((u32)f2b(b0.w*i0) << 16));
            *(uint2*)(d1      ) = make_uint2((u32)f2b(a1.x*i1) | ((u32)f2b(a1.y*i1) << 16),
                                             (u32)f2b(a1.z*i1) | ((u32)f2b(a1.w*i1) << 16));
            *(uint2*)(d1 + 256) = make_uint2((u32)f2b(b1.x*i1) | ((u32)f2b(b1.y*i1) << 16),
                                             (u32)f2b(b1.z*i1) | ((u32)f2b(b1.w*i1) << 16));
            *(uint2*)(d2      ) = make_uint2((u32)f2b(a2.x*i2) | ((u32)f2b(a2.y*i2) << 16),
                                             (u32)f2b(a2.z*i2) | ((u32)f2b(a2.w*i2) << 16));
            *(uint2*)(d2 + 256) = make_uint2((u32)f2b(b2.x*i2) | ((u32)f2b(b2.y*i2) << 16),
                                             (u32)f2b(b2.z*i2) | ((u32)f2b(b2.w*i2) << 16));
            *(uint2*)(d3      ) = make_uint2((u32)f2b(a3.x*i3) | ((u32)f2b(a3.y*i3) << 16),
                                             (u32)f2b(a3.z*i3) | ((u32)f2b(a3.w*i3) << 16));
            *(uint2*)(d3 + 256) = make_uint2((u32)f2b(b3.x*i3) | ((u32)f2b(b3.y*i3) << 16),
                                             (u32)f2b(b3.z*i3) | ((u32)f2b(b3.w*i3) << 16));
        }
    }
}

// ---------------- Kernel 3: GEMM h = pooled @ W1^T, + bias + exact GELU ----------------
#define GBM 128
#define GBN 128
#define GBK 64
__global__ __launch_bounds__(256) void k_gemm(
    const u16* __restrict__ A, const u16* __restrict__ Bw,
    const float* __restrict__ bias, float* __restrict__ H)
{
    __shared__ u16 As[GBM * GBK];   // 16 KB, logical [128][64], groups of 8 swizzled
    __shared__ u16 Bs[GBN * GBK];   // 16 KB

    const int tid  = threadIdx.x;
    const int lane = tid & 63;
    const int wid  = tid >> 6;                 // 0..3
    const int wr   = wid >> 1;                 // 0..1 (row quadrant)
    const int wc   = wid & 1;                  // 0..1 (col quadrant)
    const int brow = blockIdx.y * GBM;
    const int bcol = blockIdx.x * GBN;

    const int lrow = lane & 15;
    const int lko  = (lane >> 4) * 8;          // k sub-offset within 32
    const int gsub = lko >> 3;                 // 0..3 (group within kk half)

    f32x4 acc[4][4];
    #pragma unroll
    for (int m = 0; m < 4; ++m)
        #pragma unroll
        for (int n = 0; n < 4; ++n)
            acc[m][n] = (f32x4){0.f, 0.f, 0.f, 0.f};

    for (int kt = 0; kt < KDIM / GBK; ++kt) {
        const int k0 = kt * GBK;
        #pragma unroll
        for (int i = 0; i < 4; ++i) {
            int f   = i * 256 + tid;           // 0..1023
            int row = f >> 3;
            int gl  = (f & 7) ^ (row & 7);     // source (logical) group
            const u16* srcA = A  + (size_t)(brow + row) * KDIM + k0 + gl * 8;
            const u16* srcB = Bw + (size_t)(bcol + row) * KDIM + k0 + gl * 8;
            __builtin_amdgcn_global_load_lds(
                (const __attribute__((address_space(1))) void*)srcA,
                (__attribute__((address_space(3))) void*)&As[f * 8], 16, 0, 0);
            __builtin_amdgcn_global_load_lds(
                (const __attribute__((address_space(1))) void*)srcB,
                (__attribute__((address_space(3))) void*)&Bs[f * 8], 16, 0, 0);
        }
        __syncthreads();
        #pragma unroll
        for (int kk = 0; kk < 2; ++kk) {
            const int glog = kk * 4 + gsub;    // logical group 0..7
            short8 bfrag[4];
            #pragma unroll
            for (int n = 0; n < 4; ++n) {
                int row = wc * 64 + n * 16 + lrow;
                bfrag[n] = *(const short8*)&Bs[row * GBK + ((glog ^ (row & 7)) * 8)];
            }
            #pragma unroll
            for (int m = 0; m < 4; ++m) {
                int row = wr * 64 + m * 16 + lrow;
                short8 afrag = *(const short8*)&As[row * GBK + ((glog ^ (row & 7)) * 8)];
                #pragma unroll
                for (int n = 0; n < 4; ++n)
                    acc[m][n] = __builtin_amdgcn_mfma_f32_16x16x32_bf16(
                        afrag, bfrag[n], acc[m][n], 0, 0, 0);
            }
        }
        __syncthreads();
    }

    #pragma unroll
    for (int m = 0; m < 4; ++m) {
        const int row0 = brow + wr * 64 + m * 16 + (lane >> 4) * 4;
        #pragma unroll
        for (int n = 0; n < 4; ++n) {
            const int col = bcol + wc * 64 + n * 16 + (lane & 15);
            const float bv = bias[col];
            #pragma unroll
            for (int r = 0; r < 4; ++r) {
                float x = acc[m][n][r] + bv;
                float g = 0.5f * x * (1.0f + erff(x * 0.70710678118654752f));
                H[(size_t)(row0 + r) * EMB + col] = g;
            }
        }
    }
}

// ---------------- Kernel 4: BN partial stats (deterministic, no atomics) ----------------
__global__ __launch_bounds__(512) void k_stats(const float* __restrict__ H,
                                               float* __restrict__ psum,
                                               float* __restrict__ psq)
{
    const int f = threadIdx.x;   // 0..511
    const int j = blockIdx.x;    // 0..255
    const float* p = H + (size_t)j * 32 * EMB + f;
    float s = 0.f, ss = 0.f;
    #pragma unroll 4
    for (int r = 0; r < 32; ++r) {
        float v = p[(size_t)r * EMB];
        s += v; ss += v * v;
    }
    psum[j * EMB + f] = s;
    psq [j * EMB + f] = ss;
}

// ---------------- Kernel 5: fold BN + W2 into coeff[512] and const ----------------
__global__ __launch_bounds__(512) void k_fin(const float* __restrict__ psum,
                                             const float* __restrict__ psq,
                                             const float* __restrict__ gamma,
                                             const float* __restrict__ beta,
                                             const float* __restrict__ W2,
                                             const float* __restrict__ b2,
                                             float* __restrict__ coeff)
{
    const int f = threadIdx.x;
    float s = 0.f, ss = 0.f;
    for (int j = 0; j < 256; ++j) { s += psum[j * EMB + f]; ss += psq[j * EMB + f]; }
    const float invB = 1.0f / 8192.0f;
    float mu  = s * invB;
    float var = ss * invB - mu * mu;
    float rs  = rsqrtf(var + 1e-5f);
    float c   = gamma[f] * rs * W2[f];
    coeff[f]  = c;
    float kterm = beta[f] * W2[f] - mu * c;

    __shared__ float red[512];
    red[f] = kterm;
    __syncthreads();
    for (int s2 = 256; s2 > 0; s2 >>= 1) {
        if (f < s2) red[f] += red[f + s2];
        __syncthreads();
    }
    if (f == 0) coeff[512] = red[0] + b2[0];
}

// ---------------- Kernel 6: logits[b] = dot(h[b,:], coeff) + const ----------------
__global__ __launch_bounds__(64) void k_logits(const float* __restrict__ H,
                                               const float* __restrict__ coeff,
                                               float* __restrict__ out)
{
    const int b = blockIdx.x;
    const int l = threadIdx.x;   // 0..63
    const float4* hp = (const float4*)(H + (size_t)b * EMB);
    const float4* cp = (const float4*)coeff;
    float4 h0 = hp[l],      c0 = cp[l];
    float4 h1 = hp[l + 64], c1 = cp[l + 64];
    float p = h0.x * c0.x + h0.y * c0.y + h0.z * c0.z + h0.w * c0.w
            + h1.x * c1.x + h1.y * c1.y + h1.z * c1.z + h1.w * c1.w;
    #pragma unroll
    for (int off = 32; off > 0; off >>= 1) p += __shfl_down(p, off);
    if (l == 0) out[b] = p + coeff[512];
}

extern "C" void kernel_launch(void* const* d_in, const int* in_sizes, int n_in,
                              void* d_out, int out_size, void* d_ws, size_t ws_size,
                              hipStream_t stream) {
    (void)in_sizes; (void)n_in; (void)out_size; (void)ws_size;
    const float* qv    = (const float*)d_in[0];
    const float* vqu   = (const float*)d_in[1];
    const int*   qlen  = (const int*)d_in[2];
    const float* av    = (const float*)d_in[3];
    const float* van   = (const float*)d_in[4];
    const int*   alen  = (const int*)d_in[5];
    const float* W1    = (const float*)d_in[6];
    const float* b1    = (const float*)d_in[7];
    const float* gamma = (const float*)d_in[8];
    const float* beta  = (const float*)d_in[9];
    const float* W2    = (const float*)d_in[10];
    const float* b2    = (const float*)d_in[11];
    float* out = (float*)d_out;

    char* ws = (char*)d_ws;
    u16*   pooled = (u16*)(ws);                      // 8192*2048*2      = 33,554,432
    u16*   w1b    = (u16*)(ws + 33554432);           // 512*2048*2       =  2,097,152
    float* H      = (float*)(ws + 35651584);         // 8192*512*4       = 16,777,216
    float* psum   = (float*)(ws + 52428800);         // 256*512*4        =    524,288
    float* psq    = (float*)(ws + 52953088);         // 256*512*4        =    524,288
    float* coeff  = (float*)(ws + 53477376);         // 513*4

    k_w1    <<<dim3(1024),   dim3(256), 0, stream>>>((const float4*)W1, w1b);
    k_pool  <<<dim3(512),    dim3(256), 0, stream>>>(qv, vqu, qlen, av, van, alen, pooled);
    k_gemm  <<<dim3(4, 64),  dim3(256), 0, stream>>>(pooled, w1b, b1, H);
    k_stats <<<dim3(256),    dim3(512), 0, stream>>>(H, psum, psq);
    k_fin   <<<dim3(1),      dim3(512), 0, stream>>>(psum, psq, gamma, beta, W2, b2, coeff);
    k_logits<<<dim3(8192),   dim3(64),  0, stream>>>(H, coeff, out);
}